// Round 7
// baseline (31.678 us; speedup 1.0000x reference)
//
#include <hip/hip_runtime.h>
#include <math.h>

// B=4, K=256, D=128, H=4, alpha=0.2
// leaky(s) = 0.6*s + 0.4*|s|  (exact for alpha=0.2)
// e_ij = [0.6*(a.Lp_i) cancels in softmax] + 0.6*(a.R_j) + sum_d (0.4 a_d)|Lp_id + R_jd| + bias_ij
// mean_h(P_h @ x) = (mean_h P_h) @ x  ->  k2 writes 0.25*P per head (bf16); k3 sums + single PV.
constexpr int Kc = 256, Dc = 128, Mc = 1024;    // Mc = B*K
constexpr int HMD = 4 * Mc * Dc;                // 524288 elements per plane

__device__ inline unsigned int f2bf(float f) {      // fp32 -> bf16 bits (RNE)
    unsigned int u = __float_as_uint(f);
    return (u + 0x7FFFu + ((u >> 16) & 1u)) >> 16;
}
__device__ inline float bf2f_lo(unsigned int u) { return __uint_as_float(u << 16); }
__device__ inline float bf2f_hi(unsigned int u) { return __uint_as_float(u & 0xFFFF0000u); }

// ---------------------------------------------------------------------------
// K1 (512 blocks, 256 thr, 2 blocks/CU): 32x64-tile fp32 GEMM, 2x4 reg block.
//   bid <  256 : Lp[h][m][d] = x@W_src + lin_b          (fp32, native layout)
//   bid >= 256 : Rt[(h*4+b)][d][j] = (x@W_dst)^T        (bf16, transposed)
//                + eb[(hb*4+dt)][j] = 1.5 * sum_{d in 32-slice} 0.4*a_d*R_jd
// ---------------------------------------------------------------------------
__global__ __launch_bounds__(256) void k1(const float* __restrict__ x,
                                          const float* __restrict__ W,
                                          const float* __restrict__ lin_b,
                                          const float* __restrict__ a,
                                          float* __restrict__ Lp,
                                          unsigned short* __restrict__ Rt,
                                          float* __restrict__ eb) {
    __shared__ float As[128][32];   // [k][m-role] 16 KB
    __shared__ float Bs[128][64];   // [k][n-role] 32 KB
    __shared__ float red[4][16][4];

    const int tid = threadIdx.x;
    const int bid = blockIdx.x;
    const int tx = tid & 15, ty = tid >> 4;   // ty 0..15
    const bool isL = (bid < 256);

    int h, b, m0, n0, dt;
    if (isL) {
        const int nt = bid & 1, mt = (bid >> 1) & 31;
        h = (bid >> 6) & 3;
        m0 = mt * 32; n0 = nt * 64; b = 0; dt = 0;
        // As[k][m_l] = x[m0+m_l][k]
        {
            const int m_l = tid & 31, kq = tid >> 5;   // 8 k-slices of 16
            #pragma unroll
            for (int c = 0; c < 4; ++c) {
                const int k0 = kq * 16 + c * 4;
                const float4 v = *(const float4*)&x[(m0 + m_l) * Dc + k0];
                As[k0 + 0][m_l] = v.x; As[k0 + 1][m_l] = v.y;
                As[k0 + 2][m_l] = v.z; As[k0 + 3][m_l] = v.w;
            }
        }
        // Bs[k][n_l] = W_src[k][n0+n_l]
        {
            const int n_l = tid & 63, kq = tid >> 6;
            const float* Wb = W + (h * 2) * Dc * Dc;
            #pragma unroll
            for (int kk = 0; kk < 32; ++kk) {
                const int k = kq * 32 + kk;
                Bs[k][n_l] = Wb[k * Dc + n0 + n_l];
            }
        }
    } else {
        const int r_ = bid - 256;
        const int jt = r_ & 3;
        dt = (r_ >> 2) & 3;
        b  = (r_ >> 4) & 3;
        h  = (r_ >> 6) & 3;
        m0 = dt * 32;          // m-role = d
        n0 = jt * 64;          // n-role = j
        // As[k][d_l] = W_dst[k][m0+d_l]
        {
            const int d_l = tid & 31, kq = tid >> 5;
            const float* Wb = W + ((h * 2 + 1) * Dc) * Dc;
            #pragma unroll
            for (int kk = 0; kk < 16; ++kk) {
                const int k = kq * 16 + kk;
                As[k][d_l] = Wb[k * Dc + m0 + d_l];
            }
        }
        // Bs[k][j_l] = x[b*256 + n0 + j_l][k]
        {
            const int j_l = tid & 63, kq = tid >> 6;
            #pragma unroll
            for (int c = 0; c < 8; ++c) {
                const int k0 = kq * 32 + c * 4;
                const float4 v = *(const float4*)&x[(b * Kc + n0 + j_l) * Dc + k0];
                Bs[k0 + 0][j_l] = v.x; Bs[k0 + 1][j_l] = v.y;
                Bs[k0 + 2][j_l] = v.z; Bs[k0 + 3][j_l] = v.w;
            }
        }
    }
    __syncthreads();

    float acc[2][4];
    #pragma unroll
    for (int r = 0; r < 2; ++r)
        #pragma unroll
        for (int c = 0; c < 4; ++c) acc[r][c] = 0.f;

    #pragma unroll 16
    for (int k = 0; k < 128; ++k) {
        const float2 xa = *(const float2*)&As[k][ty * 2];
        const float4 wb = *(const float4*)&Bs[k][tx * 4];
        acc[0][0] = fmaf(xa.x, wb.x, acc[0][0]);
        acc[0][1] = fmaf(xa.x, wb.y, acc[0][1]);
        acc[0][2] = fmaf(xa.x, wb.z, acc[0][2]);
        acc[0][3] = fmaf(xa.x, wb.w, acc[0][3]);
        acc[1][0] = fmaf(xa.y, wb.x, acc[1][0]);
        acc[1][1] = fmaf(xa.y, wb.y, acc[1][1]);
        acc[1][2] = fmaf(xa.y, wb.z, acc[1][2]);
        acc[1][3] = fmaf(xa.y, wb.w, acc[1][3]);
    }

    if (isL) {
        const float4 lv = *(const float4*)&lin_b[h * Dc + n0 + tx * 4];
        float* dst = Lp + h * (Mc * Dc);
        #pragma unroll
        for (int r = 0; r < 2; ++r) {
            float4 o;
            o.x = acc[r][0] + lv.x; o.y = acc[r][1] + lv.y;
            o.z = acc[r][2] + lv.z; o.w = acc[r][3] + lv.w;
            *(float4*)&dst[(m0 + ty * 2 + r) * Dc + n0 + tx * 4] = o;
        }
    } else {
        unsigned short* dst = Rt + ((h * 4 + b) * Dc + m0) * Kc + n0;
        #pragma unroll
        for (int r = 0; r < 2; ++r) {
            uint2 pk;
            pk.x = f2bf(acc[r][0]) | (f2bf(acc[r][1]) << 16);
            pk.y = f2bf(acc[r][2]) | (f2bf(acc[r][3]) << 16);
            *(uint2*)&dst[(ty * 2 + r) * Kc + tx * 4] = pk;
        }
        // eb partial: p_c = 0.4 * sum_r a[m0+ty*2+r] * acc[r][c]
        const float2 av = *(const float2*)&a[h * Dc + m0 + ty * 2];
        float p0 = 0.4f * (av.x * acc[0][0] + av.y * acc[1][0]);
        float p1 = 0.4f * (av.x * acc[0][1] + av.y * acc[1][1]);
        float p2 = 0.4f * (av.x * acc[0][2] + av.y * acc[1][2]);
        float p3 = 0.4f * (av.x * acc[0][3] + av.y * acc[1][3]);
        // reduce over the 4 ty values within each wave (tid bits 4..5)
        p0 += __shfl_xor(p0, 16, 64); p0 += __shfl_xor(p0, 32, 64);
        p1 += __shfl_xor(p1, 16, 64); p1 += __shfl_xor(p1, 32, 64);
        p2 += __shfl_xor(p2, 16, 64); p2 += __shfl_xor(p2, 32, 64);
        p3 += __shfl_xor(p3, 16, 64); p3 += __shfl_xor(p3, 32, 64);
        if (((tid >> 4) & 3) == 0) {
            const int w = tid >> 6;
            red[w][tx][0] = p0; red[w][tx][1] = p1;
            red[w][tx][2] = p2; red[w][tx][3] = p3;
        }
        __syncthreads();
        if (tid < 64) {
            const int txl = tid >> 2, c = tid & 3;
            const float v = red[0][txl][c] + red[1][txl][c] + red[2][txl][c] + red[3][txl][c];
            eb[((h * 4 + b) * 4 + dt) * Kc + n0 + tid] = 1.5f * v;
        }
    }
}

// ---------------------------------------------------------------------------
// K2 (2048 blocks = (hb, 128 i-tiles of 2 rows), 256 thr, 8 blocks/CU = full
// occupancy): thread (dq=tid>>6, j4=tid&63) owns acc[2i][4j] over a 32-d
// slice; Rt (bf16) from global (L2, XCD-pinned). Padded-LDS dq-reduce ->
// wave-per-row shuffle softmax (waves 0,1) -> write 0.25*P (bf16) to Pws.
// ---------------------------------------------------------------------------
#define EROW(ACC, LPV)                                            \
    ACC.x = fmaf(aad, __builtin_fabsf((LPV) + rx), ACC.x);        \
    ACC.y = fmaf(aad, __builtin_fabsf((LPV) + ry), ACC.y);        \
    ACC.z = fmaf(aad, __builtin_fabsf((LPV) + rz), ACC.z);        \
    ACC.w = fmaf(aad, __builtin_fabsf((LPV) + rw), ACC.w);

__global__ __launch_bounds__(256) void k2(const float* __restrict__ a,
                                          const float* __restrict__ bias,
                                          const float* __restrict__ Lp,
                                          const unsigned short* __restrict__ Rt,
                                          const float* __restrict__ eb,
                                          unsigned short* __restrict__ Pws) {
    __shared__ float red[256 * 12];   // 12 KB dq-reduce scratch (stride 12: 16B-aligned pad)
    __shared__ float lpT[Dc * 2];     // [d][i] 1 KB
    __shared__ float aa[Dc];          // 0.4*a[h]

    const int tid = threadIdx.x;
    const int L = blockIdx.x;
    // XCD-pin: consecutive blockIdx round-robin across XCDs (heuristic).
    const int xcd = L & 7, q = L >> 3;       // q 0..255
    const int hb = (xcd << 1) | (q & 1);     // 2 planes per XCD
    const int it = q >> 1;                   // 0..127
    const int h = hb >> 2, b = hb & 3;
    const int i0 = it * 2;

    {
        const int d_s = tid & 127, half = tid >> 7;
        lpT[d_s * 2 + half] = Lp[(h * Mc + b * Kc + i0 + half) * Dc + d_s];
    }
    if (tid < 128) aa[tid] = 0.4f * a[h * Dc + tid];
    __syncthreads();

    const int dq = tid >> 6, j4 = tid & 63;
    float4 acc0 = make_float4(0.f, 0.f, 0.f, 0.f);
    float4 acc1 = make_float4(0.f, 0.f, 0.f, 0.f);
    {
        const unsigned short* rb = Rt + (hb * Dc + dq * 32) * Kc + j4 * 4;
        const float* lt = lpT + dq * 32 * 2;
        const float* at = aa + dq * 32;
        #pragma unroll 8
        for (int dd = 0; dd < 32; ++dd) {
            const uint2 rp = *(const uint2*)(rb + dd * Kc);     // 4 bf16, 512B/wave coalesced
            const float rx = bf2f_lo(rp.x), ry = bf2f_hi(rp.x);
            const float rz = bf2f_lo(rp.y), rw = bf2f_hi(rp.y);
            const float aad = at[dd];                           // LDS broadcast
            const float2 l2 = *(const float2*)(lt + dd * 2);    // LDS broadcast b64
            EROW(acc0, l2.x);
            EROW(acc1, l2.y);
        }
    }
    {
        float* myred = red + tid * 12;
        *(float4*)&myred[0] = acc0;
        *(float4*)&myred[4] = acc1;
    }
    __syncthreads();

    // softmax: wave w (0,1) owns row i0+w; lane l = j-quad
    const int w = tid >> 6, l = tid & 63;
    if (w < 2) {
        float4 e0 = make_float4(0.f, 0.f, 0.f, 0.f);
        #pragma unroll
        for (int q4 = 0; q4 < 4; ++q4) {
            const float4 v = *(const float4*)&red[(q4 * 64 + l) * 12 + w * 4];
            e0.x += v.x; e0.y += v.y; e0.z += v.z; e0.w += v.w;
        }
        float4 ebs = make_float4(0.f, 0.f, 0.f, 0.f);
        #pragma unroll
        for (int seg = 0; seg < 4; ++seg) {
            const float4 v = *(const float4*)&eb[(hb * 4 + seg) * Kc + l * 4];
            ebs.x += v.x; ebs.y += v.y; ebs.z += v.z; ebs.w += v.w;
        }
        const float4 bv = *(const float4*)&bias[(h * Kc + i0 + w) * Kc + l * 4];
        e0.x += ebs.x + bv.x;
        e0.y += ebs.y + bv.y;
        e0.z += ebs.z + bv.z;
        e0.w += ebs.w + bv.w;

        float m = fmaxf(fmaxf(e0.x, e0.y), fmaxf(e0.z, e0.w));
        #pragma unroll
        for (int off = 1; off < 64; off <<= 1) m = fmaxf(m, __shfl_xor(m, off, 64));
        const float p0 = __expf(e0.x - m), p1 = __expf(e0.y - m);
        const float p2 = __expf(e0.z - m), p3 = __expf(e0.w - m);
        float s = p0 + p1 + p2 + p3;
        #pragma unroll
        for (int off = 1; off < 64; off <<= 1) s += __shfl_xor(s, off, 64);
        const float sc = 0.25f / s;     // fold mean over H
        uint2 pk;
        pk.x = f2bf(p0 * sc) | (f2bf(p1 * sc) << 16);
        pk.y = f2bf(p2 * sc) | (f2bf(p3 * sc) << 16);
        *(uint2*)&Pws[(hb * Kc + i0 + w) * Kc + l * 4] = pk;
    }
}

// ---------------------------------------------------------------------------
// K3 (512 blocks = (b, 128 i-tiles of 2 rows), 256 thr): P-bar = sum_h Pws(bf16),
// then single PV: out[i][d] = sum_j Pbar[i][j] * x[b][j][d].
// ---------------------------------------------------------------------------
__global__ __launch_bounds__(256) void k3(const float* __restrict__ x,
                                          const unsigned short* __restrict__ Pws,
                                          float* __restrict__ out) {
    __shared__ float pbar[2 * Kc];    // 2 KB
    __shared__ float red[256 * 12];   // 12 KB jq-reduce scratch

    const int tid = threadIdx.x;
    const int bid = blockIdx.x;
    const int b = bid >> 7, it = bid & 127;
    const int i0 = it * 2;

    if (tid < 128) {
        const int r = tid >> 6, c = tid & 63;
        float4 s = make_float4(0.f, 0.f, 0.f, 0.f);
        #pragma unroll
        for (int h = 0; h < 4; ++h) {
            const uint2 v = *(const uint2*)&Pws[((h * 4 + b) * Kc + i0 + r) * Kc + c * 4];
            s.x += bf2f_lo(v.x); s.y += bf2f_hi(v.x);
            s.z += bf2f_lo(v.y); s.w += bf2f_hi(v.y);
        }
        *(float4*)&pbar[r * Kc + c * 4] = s;
    }
    __syncthreads();

    const int jq = tid >> 5, dd4 = tid & 31;
    float4 o0 = make_float4(0.f, 0.f, 0.f, 0.f);
    float4 o1 = make_float4(0.f, 0.f, 0.f, 0.f);
    {
        const float* xb = x + (b * Kc) * Dc + dd4 * 4;
        #pragma unroll 4
        for (int jj = 0; jj < 32; ++jj) {
            const int j = jj * 8 + jq;
            const float4 xv = *(const float4*)(xb + j * Dc);   // global, L2-hot
            const float pv0 = pbar[j];                          // LDS broadcast
            const float pv1 = pbar[Kc + j];
            o0.x = fmaf(pv0, xv.x, o0.x); o0.y = fmaf(pv0, xv.y, o0.y);
            o0.z = fmaf(pv0, xv.z, o0.z); o0.w = fmaf(pv0, xv.w, o0.w);
            o1.x = fmaf(pv1, xv.x, o1.x); o1.y = fmaf(pv1, xv.y, o1.y);
            o1.z = fmaf(pv1, xv.z, o1.z); o1.w = fmaf(pv1, xv.w, o1.w);
        }
    }
    {
        float* myred = red + (jq * 32 + dd4) * 12;
        *(float4*)&myred[0] = o0;
        *(float4*)&myred[4] = o1;
    }
    __syncthreads();
    if (tid < 64) {
        const int i_f = tid >> 5, dd_f = tid & 31;
        float4 s = make_float4(0.f, 0.f, 0.f, 0.f);
        #pragma unroll
        for (int q = 0; q < 8; ++q) {
            const float4 v = *(const float4*)&red[(q * 32 + dd_f) * 12 + i_f * 4];
            s.x += v.x; s.y += v.y; s.z += v.z; s.w += v.w;
        }
        *(float4*)&out[(b * Kc + i0 + i_f) * Dc + dd_f * 4] = s;
    }
}

extern "C" void kernel_launch(void* const* d_in, const int* in_sizes, int n_in,
                              void* d_out, int out_size, void* d_ws, size_t ws_size,
                              hipStream_t stream) {
    const float* x     = (const float*)d_in[0];
    const float* W     = (const float*)d_in[1];
    const float* lin_b = (const float*)d_in[2];
    const float* a     = (const float*)d_in[3];
    const float* bias  = (const float*)d_in[4];
    float* out = (float*)d_out;

    float*          Lp  = (float*)d_ws;                       // fp32 [H][M][D]
    unsigned short* Rt  = (unsigned short*)(Lp + HMD);        // bf16 [(H*B)][D][K]
    float*          eb  = (float*)(Rt + HMD);                 // fp32 [(H*B)*4][K]
    unsigned short* Pws = (unsigned short*)(eb + 16384);      // bf16 [(H*B)][K][K]

    k1<<<512, 256, 0, stream>>>(x, W, lin_b, a, Lp, Rt, eb);
    k2<<<2048, 256, 0, stream>>>(a, bias, Lp, Rt, eb, Pws);
    k3<<<512, 256, 0, stream>>>(x, Pws, out);
}

// Round 8
// 26.743 us; speedup vs baseline: 1.1846x; 1.1846x over previous
//
#include <hip/hip_runtime.h>
#include <math.h>

// B=4, K=256, D=128, H=4, alpha=0.2
// leaky(s) = 0.6*s + 0.4*|s|  (exact for alpha=0.2)
// e_ij = [0.6*(a.Lp_i) cancels in softmax] + 0.6*(a.R_j) + sum_d (0.4 a_d)|Lp_id + R_jd| + bias_ij
// mean_h(P_h @ x) = (mean_h P_h) @ x  ->  k2 writes 0.25*P per head (bf16); k3 sums + single PV.
// Lp/Rt stored as packed-f16 d-pairs; k2 inner loop = pk_add + and(abs) + v_dot2_f32_f16.
constexpr int Kc = 256, Dc = 128, Mc = 1024;    // Mc = B*K

typedef _Float16 h2_t __attribute__((ext_vector_type(2)));
union U32H2 { unsigned int u; h2_t h; };
__device__ inline h2_t u2h(unsigned int u) { U32H2 x; x.u = u; return x.h; }
__device__ inline unsigned int h2u(h2_t h) { U32H2 x; x.h = h; return x.u; }
__device__ inline unsigned int packh(float a, float b) {
    h2_t h; h.x = (_Float16)a; h.y = (_Float16)b; return h2u(h);
}
__device__ inline unsigned int f2bf(float f) {      // fp32 -> bf16 bits (RNE)
    unsigned int u = __float_as_uint(f);
    return (u + 0x7FFFu + ((u >> 16) & 1u)) >> 16;
}
__device__ inline float bf2f_lo(unsigned int u) { return __uint_as_float(u << 16); }
__device__ inline float bf2f_hi(unsigned int u) { return __uint_as_float(u & 0xFFFF0000u); }

// acc += (0.4a_2d)|l_2d + r_2d| + (0.4a_2d+1)|l_2d+1 + r_2d+1|, f32 accumulate
__device__ inline float estep(unsigned int r, unsigned int l, h2_t av, float acc) {
    h2_t s = u2h(r) + u2h(l);                       // v_pk_add_f16
    unsigned int t = h2u(s) & 0x7FFF7FFFu;          // packed abs
#if __has_builtin(__builtin_amdgcn_fdot2)
    return __builtin_amdgcn_fdot2(u2h(t), av, acc, false);   // v_dot2_f32_f16
#else
    h2_t th = u2h(t);
    return fmaf((float)th.x, (float)av.x, fmaf((float)th.y, (float)av.y, acc));
#endif
}

// ---------------------------------------------------------------------------
// K1 (512 blocks, 256 thr, 2 blocks/CU): 32x64-tile fp32 GEMM, 2x4 reg block.
//   bid <  256 : Lpp[h][m][dp] = packed-f16 pair of (x@W_src + lin_b)
//   bid >= 256 : Rtp[hb][dp][j] = packed-f16 pair of (x@W_dst)^T
//                + eb[(hb*4+dt)][j] = 1.5 * sum_{d in 32-slice} 0.4*a_d*R_jd (fp32)
// ---------------------------------------------------------------------------
__global__ __launch_bounds__(256) void k1(const float* __restrict__ x,
                                          const float* __restrict__ W,
                                          const float* __restrict__ lin_b,
                                          const float* __restrict__ a,
                                          unsigned int* __restrict__ Lpp,
                                          unsigned int* __restrict__ Rtp,
                                          float* __restrict__ eb) {
    __shared__ float As[128][32];   // [k][m-role] 16 KB
    __shared__ float Bs[128][64];   // [k][n-role] 32 KB
    __shared__ float red[4][16][4];

    const int tid = threadIdx.x;
    const int bid = blockIdx.x;
    const int tx = tid & 15, ty = tid >> 4;   // ty 0..15
    const bool isL = (bid < 256);

    int h, b, m0, n0, dt;
    if (isL) {
        const int nt = bid & 1, mt = (bid >> 1) & 31;
        h = (bid >> 6) & 3;
        m0 = mt * 32; n0 = nt * 64; b = 0; dt = 0;
        {
            const int m_l = tid & 31, kq = tid >> 5;
            #pragma unroll
            for (int c = 0; c < 4; ++c) {
                const int k0 = kq * 16 + c * 4;
                const float4 v = *(const float4*)&x[(m0 + m_l) * Dc + k0];
                As[k0 + 0][m_l] = v.x; As[k0 + 1][m_l] = v.y;
                As[k0 + 2][m_l] = v.z; As[k0 + 3][m_l] = v.w;
            }
        }
        {
            const int n_l = tid & 63, kq = tid >> 6;
            const float* Wb = W + (h * 2) * Dc * Dc;
            #pragma unroll
            for (int kk = 0; kk < 32; ++kk) {
                const int k = kq * 32 + kk;
                Bs[k][n_l] = Wb[k * Dc + n0 + n_l];
            }
        }
    } else {
        const int r_ = bid - 256;
        const int jt = r_ & 3;
        dt = (r_ >> 2) & 3;
        b  = (r_ >> 4) & 3;
        h  = (r_ >> 6) & 3;
        m0 = dt * 32;          // m-role = d
        n0 = jt * 64;          // n-role = j
        {
            const int d_l = tid & 31, kq = tid >> 5;
            const float* Wb = W + ((h * 2 + 1) * Dc) * Dc;
            #pragma unroll
            for (int kk = 0; kk < 16; ++kk) {
                const int k = kq * 16 + kk;
                As[k][d_l] = Wb[k * Dc + m0 + d_l];
            }
        }
        {
            const int j_l = tid & 63, kq = tid >> 6;
            #pragma unroll
            for (int c = 0; c < 8; ++c) {
                const int k0 = kq * 32 + c * 4;
                const float4 v = *(const float4*)&x[(b * Kc + n0 + j_l) * Dc + k0];
                Bs[k0 + 0][j_l] = v.x; Bs[k0 + 1][j_l] = v.y;
                Bs[k0 + 2][j_l] = v.z; Bs[k0 + 3][j_l] = v.w;
            }
        }
    }
    __syncthreads();

    float acc[2][4];
    #pragma unroll
    for (int r = 0; r < 2; ++r)
        #pragma unroll
        for (int c = 0; c < 4; ++c) acc[r][c] = 0.f;

    #pragma unroll 16
    for (int k = 0; k < 128; ++k) {
        const float2 xa = *(const float2*)&As[k][ty * 2];
        const float4 wb = *(const float4*)&Bs[k][tx * 4];
        acc[0][0] = fmaf(xa.x, wb.x, acc[0][0]);
        acc[0][1] = fmaf(xa.x, wb.y, acc[0][1]);
        acc[0][2] = fmaf(xa.x, wb.z, acc[0][2]);
        acc[0][3] = fmaf(xa.x, wb.w, acc[0][3]);
        acc[1][0] = fmaf(xa.y, wb.x, acc[1][0]);
        acc[1][1] = fmaf(xa.y, wb.y, acc[1][1]);
        acc[1][2] = fmaf(xa.y, wb.z, acc[1][2]);
        acc[1][3] = fmaf(xa.y, wb.w, acc[1][3]);
    }

    if (isL) {
        // pack along d (n-role): pairs (tx*4, tx*4+1), (tx*4+2, tx*4+3)
        const float4 lv = *(const float4*)&lin_b[h * Dc + n0 + tx * 4];
        #pragma unroll
        for (int r = 0; r < 2; ++r) {
            uint2 pk;
            pk.x = packh(acc[r][0] + lv.x, acc[r][1] + lv.y);
            pk.y = packh(acc[r][2] + lv.z, acc[r][3] + lv.w);
            *(uint2*)&Lpp[(h * Mc + m0 + ty * 2 + r) * 64 + (n0 >> 1) + tx * 2] = pk;
        }
    } else {
        // pack along d (m-role): thread owns consecutive d rows m0+ty*2, +1
        {
            uint4 pk;
            pk.x = packh(acc[0][0], acc[1][0]);
            pk.y = packh(acc[0][1], acc[1][1]);
            pk.z = packh(acc[0][2], acc[1][2]);
            pk.w = packh(acc[0][3], acc[1][3]);
            *(uint4*)&Rtp[((h * 4 + b) * 64 + (m0 >> 1) + ty) * Kc + n0 + tx * 4] = pk;
        }
        const float2 av = *(const float2*)&a[h * Dc + m0 + ty * 2];
        float p0 = 0.4f * (av.x * acc[0][0] + av.y * acc[1][0]);
        float p1 = 0.4f * (av.x * acc[0][1] + av.y * acc[1][1]);
        float p2 = 0.4f * (av.x * acc[0][2] + av.y * acc[1][2]);
        float p3 = 0.4f * (av.x * acc[0][3] + av.y * acc[1][3]);
        p0 += __shfl_xor(p0, 16, 64); p0 += __shfl_xor(p0, 32, 64);
        p1 += __shfl_xor(p1, 16, 64); p1 += __shfl_xor(p1, 32, 64);
        p2 += __shfl_xor(p2, 16, 64); p2 += __shfl_xor(p2, 32, 64);
        p3 += __shfl_xor(p3, 16, 64); p3 += __shfl_xor(p3, 32, 64);
        if (((tid >> 4) & 3) == 0) {
            const int w = tid >> 6;
            red[w][tx][0] = p0; red[w][tx][1] = p1;
            red[w][tx][2] = p2; red[w][tx][3] = p3;
        }
        __syncthreads();
        if (tid < 64) {
            const int txl = tid >> 2, c = tid & 3;
            const float v = red[0][txl][c] + red[1][txl][c] + red[2][txl][c] + red[3][txl][c];
            eb[((h * 4 + b) * 4 + dt) * Kc + n0 + tid] = 1.5f * v;
        }
    }
}

// ---------------------------------------------------------------------------
// K2 (1024 blocks = (hb, 64 i-tiles of 4 rows), 256 thr, 4 blocks/CU,
// XCD-pinned): thread (dq=tid>>6, j4=tid&63) owns acc[4i][4j] over a 32-d
// slice (16 packed pairs). Inner step = pk_add + and + v_dot2_f32_f16.
// Padded-LDS dq-reduce -> wave-per-row shuffle softmax -> 0.25*P (bf16).
// ---------------------------------------------------------------------------
__global__ __launch_bounds__(256) void k2(const float* __restrict__ a,
                                          const float* __restrict__ bias,
                                          const unsigned int* __restrict__ Lpp,
                                          const unsigned int* __restrict__ Rtp,
                                          const float* __restrict__ eb,
                                          unsigned short* __restrict__ Pws) {
    __shared__ float red[256 * 20];      // 20 KB dq-reduce scratch
    __shared__ unsigned int lpT2[64 * 4];  // [dp][i] 1 KB packed-f16 Lp
    __shared__ unsigned int aa2s[64];      // packed-f16 0.4*a pairs

    const int tid = threadIdx.x;
    const int L = blockIdx.x;
    // XCD-pin: consecutive blockIdx round-robin across XCDs (heuristic).
    const int xcd = L & 7, q = L >> 3;       // q 0..127
    const int hb = (xcd << 1) | (q & 1);     // 2 planes per XCD
    const int it = q >> 1;                   // 0..63
    const int h = hb >> 2, b = hb & 3;
    const int i0 = it * 4;

    {
        const int i = tid & 3, dp = tid >> 2;
        lpT2[dp * 4 + i] = Lpp[(h * Mc + b * Kc + i0 + i) * 64 + dp];
    }
    if (tid < 64) aa2s[tid] = packh(0.4f * a[h * Dc + 2 * tid], 0.4f * a[h * Dc + 2 * tid + 1]);
    __syncthreads();

    const int dq = tid >> 6, j4 = tid & 63;
    float4 acc0 = make_float4(0.f, 0.f, 0.f, 0.f);
    float4 acc1 = make_float4(0.f, 0.f, 0.f, 0.f);
    float4 acc2 = make_float4(0.f, 0.f, 0.f, 0.f);
    float4 acc3 = make_float4(0.f, 0.f, 0.f, 0.f);
    {
        const unsigned int* rb = Rtp + (hb * 64 + dq * 16) * Kc + j4 * 4;
        const unsigned int* lt = lpT2 + dq * 16 * 4;
        const unsigned int* at = aa2s + dq * 16;
        #pragma unroll
        for (int dp = 0; dp < 16; ++dp) {
            const uint4 rr = *(const uint4*)(rb + dp * Kc);    // 4 j cols x 2 d (global, L2-hot)
            const uint4 lp = *(const uint4*)(lt + dp * 4);     // 4 i rows x 2 d (LDS b128)
            const h2_t av = u2h(at[dp]);                       // LDS b32 broadcast
            acc0.x = estep(rr.x, lp.x, av, acc0.x);
            acc0.y = estep(rr.y, lp.x, av, acc0.y);
            acc0.z = estep(rr.z, lp.x, av, acc0.z);
            acc0.w = estep(rr.w, lp.x, av, acc0.w);
            acc1.x = estep(rr.x, lp.y, av, acc1.x);
            acc1.y = estep(rr.y, lp.y, av, acc1.y);
            acc1.z = estep(rr.z, lp.y, av, acc1.z);
            acc1.w = estep(rr.w, lp.y, av, acc1.w);
            acc2.x = estep(rr.x, lp.z, av, acc2.x);
            acc2.y = estep(rr.y, lp.z, av, acc2.y);
            acc2.z = estep(rr.z, lp.z, av, acc2.z);
            acc2.w = estep(rr.w, lp.z, av, acc2.w);
            acc3.x = estep(rr.x, lp.w, av, acc3.x);
            acc3.y = estep(rr.y, lp.w, av, acc3.y);
            acc3.z = estep(rr.z, lp.w, av, acc3.z);
            acc3.w = estep(rr.w, lp.w, av, acc3.w);
        }
    }
    {
        float* myred = red + tid * 20;
        *(float4*)&myred[0]  = acc0;
        *(float4*)&myred[4]  = acc1;
        *(float4*)&myred[8]  = acc2;
        *(float4*)&myred[12] = acc3;
    }
    __syncthreads();

    // softmax: wave w owns row i0+w; lane l = j-quad
    {
        const int w = tid >> 6, l = tid & 63;
        float4 e0 = make_float4(0.f, 0.f, 0.f, 0.f);
        #pragma unroll
        for (int q4 = 0; q4 < 4; ++q4) {
            const float4 v = *(const float4*)&red[(q4 * 64 + l) * 20 + w * 4];
            e0.x += v.x; e0.y += v.y; e0.z += v.z; e0.w += v.w;
        }
        float4 ebs = make_float4(0.f, 0.f, 0.f, 0.f);
        #pragma unroll
        for (int seg = 0; seg < 4; ++seg) {
            const float4 v = *(const float4*)&eb[(hb * 4 + seg) * Kc + l * 4];
            ebs.x += v.x; ebs.y += v.y; ebs.z += v.z; ebs.w += v.w;
        }
        const float4 bv = *(const float4*)&bias[(h * Kc + i0 + w) * Kc + l * 4];
        e0.x += ebs.x + bv.x;
        e0.y += ebs.y + bv.y;
        e0.z += ebs.z + bv.z;
        e0.w += ebs.w + bv.w;

        float m = fmaxf(fmaxf(e0.x, e0.y), fmaxf(e0.z, e0.w));
        #pragma unroll
        for (int off = 1; off < 64; off <<= 1) m = fmaxf(m, __shfl_xor(m, off, 64));
        const float p0 = __expf(e0.x - m), p1 = __expf(e0.y - m);
        const float p2 = __expf(e0.z - m), p3 = __expf(e0.w - m);
        float s = p0 + p1 + p2 + p3;
        #pragma unroll
        for (int off = 1; off < 64; off <<= 1) s += __shfl_xor(s, off, 64);
        const float sc = 0.25f / s;     // fold mean over H
        uint2 pk;
        pk.x = f2bf(p0 * sc) | (f2bf(p1 * sc) << 16);
        pk.y = f2bf(p2 * sc) | (f2bf(p3 * sc) << 16);
        *(uint2*)&Pws[(hb * Kc + i0 + w) * Kc + l * 4] = pk;
    }
}

// ---------------------------------------------------------------------------
// K3 (512 blocks = (b, 128 i-tiles of 2 rows), 256 thr): P-bar = sum_h Pws(bf16),
// then single PV: out[i][d] = sum_j Pbar[i][j] * x[b][j][d].
// ---------------------------------------------------------------------------
__global__ __launch_bounds__(256) void k3(const float* __restrict__ x,
                                          const unsigned short* __restrict__ Pws,
                                          float* __restrict__ out) {
    __shared__ float pbar[2 * Kc];    // 2 KB
    __shared__ float red[256 * 12];   // 12 KB jq-reduce scratch

    const int tid = threadIdx.x;
    const int bid = blockIdx.x;
    const int b = bid >> 7, it = bid & 127;
    const int i0 = it * 2;

    if (tid < 128) {
        const int r = tid >> 6, c = tid & 63;
        float4 s = make_float4(0.f, 0.f, 0.f, 0.f);
        #pragma unroll
        for (int h = 0; h < 4; ++h) {
            const uint2 v = *(const uint2*)&Pws[((h * 4 + b) * Kc + i0 + r) * Kc + c * 4];
            s.x += bf2f_lo(v.x); s.y += bf2f_hi(v.x);
            s.z += bf2f_lo(v.y); s.w += bf2f_hi(v.y);
        }
        *(float4*)&pbar[r * Kc + c * 4] = s;
    }
    __syncthreads();

    const int jq = tid >> 5, dd4 = tid & 31;
    float4 o0 = make_float4(0.f, 0.f, 0.f, 0.f);
    float4 o1 = make_float4(0.f, 0.f, 0.f, 0.f);
    {
        const float* xb = x + (b * Kc) * Dc + dd4 * 4;
        #pragma unroll 4
        for (int jj = 0; jj < 32; ++jj) {
            const int j = jj * 8 + jq;
            const float4 xv = *(const float4*)(xb + j * Dc);   // global, L2-hot
            const float pv0 = pbar[j];                          // LDS broadcast
            const float pv1 = pbar[Kc + j];
            o0.x = fmaf(pv0, xv.x, o0.x); o0.y = fmaf(pv0, xv.y, o0.y);
            o0.z = fmaf(pv0, xv.z, o0.z); o0.w = fmaf(pv0, xv.w, o0.w);
            o1.x = fmaf(pv1, xv.x, o1.x); o1.y = fmaf(pv1, xv.y, o1.y);
            o1.z = fmaf(pv1, xv.z, o1.z); o1.w = fmaf(pv1, xv.w, o1.w);
        }
    }
    {
        float* myred = red + (jq * 32 + dd4) * 12;
        *(float4*)&myred[0] = o0;
        *(float4*)&myred[4] = o1;
    }
    __syncthreads();
    if (tid < 64) {
        const int i_f = tid >> 5, dd_f = tid & 31;
        float4 s = make_float4(0.f, 0.f, 0.f, 0.f);
        #pragma unroll
        for (int q = 0; q < 8; ++q) {
            const float4 v = *(const float4*)&red[(q * 32 + dd_f) * 12 + i_f * 4];
            s.x += v.x; s.y += v.y; s.z += v.z; s.w += v.w;
        }
        *(float4*)&out[(b * Kc + i0 + i_f) * Dc + dd_f * 4] = s;
    }
}

extern "C" void kernel_launch(void* const* d_in, const int* in_sizes, int n_in,
                              void* d_out, int out_size, void* d_ws, size_t ws_size,
                              hipStream_t stream) {
    const float* x     = (const float*)d_in[0];
    const float* W     = (const float*)d_in[1];
    const float* lin_b = (const float*)d_in[2];
    const float* a     = (const float*)d_in[3];
    const float* bias  = (const float*)d_in[4];
    float* out = (float*)d_out;

    unsigned int*   Lpp = (unsigned int*)d_ws;                // f16x2 [H][M][64]   (1 MB)
    unsigned int*   Rtp = Lpp + 4 * Mc * 64;                  // f16x2 [16][64][K]  (1 MB)
    float*          eb  = (float*)(Rtp + 16 * 64 * Kc);       // fp32  [16*4][K]    (64 KB)
    unsigned short* Pws = (unsigned short*)(eb + 16384);      // bf16  [16][K][K]   (2 MB)

    k1<<<512, 256, 0, stream>>>(x, W, lin_b, a, Lpp, Rtp, eb);
    k2<<<1024, 256, 0, stream>>>(a, bias, Lpp, Rtp, eb, Pws);
    k3<<<512, 256, 0, stream>>>(x, Pws, out);
}